// Round 11
// baseline (4552.057 us; speedup 1.0000x reference)
//
#include <hip/hip_runtime.h>
#include <stdint.h>

#define NB    64
#define NN    131072
#define NPTS  1024
#define TPB   512                  // 8 waves, 1 block/CU (R10-proven geometry)
#define WPB   4                    // workgroups per batch
#define NWAVE (TPB / 64)
#define CHUNK (NN / WPB)           // 32768 points per wg
#define PPT   (CHUNK / TPB)        // 64 points per thread
#define RPTS  40                   // register-resident points/thread
#define LPTS  24                   // LDS-resident points/thread (147456 B)
#define RPAIR (RPTS / 2)           // 20
#define LPAIR (LPTS / 2)           // 12
#define NPAIR (PPT / 2)            // 32 pairs, 4 scan-blocks of 8

typedef float v2f __attribute__((ext_vector_type(2)));
typedef unsigned long long u64;

static __device__ __forceinline__ v2f vmin2(v2f a, v2f b) {
#if __has_builtin(__builtin_elementwise_min)
    return __builtin_elementwise_min(a, b);
#else
    v2f r; r.x = fminf(a.x, b.x); r.y = fminf(a.y, b.y); return r;
#endif
}
static __device__ __forceinline__ v2f vmax2(v2f a, v2f b) {
#if __has_builtin(__builtin_elementwise_max)
    return __builtin_elementwise_max(a, b);
#else
    v2f r; r.x = fmaxf(a.x, b.x); r.y = fmaxf(a.y, b.y); return r;
#endif
}

// ---------------- inter-wg protocol: relaxed + stamped + COLD slots ----------
// HW LESSONS: RELAXED atomics only (R4: acq/rel at agent scope = cache-
// maintenance storm, 118x). Never reuse a spin address within a launch (R5).
// PAYLOAD=1 (ws>=8MB): slot (k,rank) = 4 u64 (cold, memset once):
//   w3 = dist_bits<<32 | (NN-1-idx)<<10 | k   (u64 max == max dist, min idx)
//   w0..w2 = x/y/z_bits<<32 | k               (each self-stamped)
// Winner publishes w3 FIRST (no coord dep), then coords; readers poll w3,
// butterfly keys, then stamp-poll the winning rank's coords (propagating
// concurrently) -> serial P[widx] reload off the critical path.
// PAYLOAD=0 fallback: R10-exact 1-word protocol + P[widx] reload.
// COMPUTE (R11): argmax tracking hoisted out of the hot loop -- loop1 is pure
// packed math (10 v_pk insts/pair) into 4 block-max accumulators; index
// recovered by a block-skipped equality scan (typically 1 of 4 blocks).

template <bool PAYLOAD>
__global__ __launch_bounds__(TPB)
__attribute__((amdgpu_waves_per_eu(2, 2)))
void fps_kernel(
    const float* __restrict__ pos,
    const int*   __restrict__ start_p,
    int*         __restrict__ out,
    u64*         __restrict__ slots)
{
#pragma clang fp contract(off)
    const int wg   = blockIdx.x;
    const int xcd  = wg & 7;            // heuristic: keep a batch's 4 wgs on one XCD
    const int sl   = wg >> 3;
    const int b    = xcd * 8 + (sl >> 2);
    const int r    = sl & 3;
    const int t    = threadIdx.x;
    const int lane = t & 63;
    const int wv   = t >> 6;

    const float* __restrict__ P  = pos + (size_t)b * NN * 3;
    const float* __restrict__ Pc = P + (size_t)r * CHUNK * 3;
    u64* __restrict__ bslots = slots +
        (PAYLOAD ? (size_t)b * NPTS * WPB * 4 : (size_t)b * NPTS * WPB);

    // pair-packed LDS: coords of points (2l, 2l+1) adjacent -> ds_read_b64
    __shared__ float lx[LPAIR * TPB * 2];   // 49152 B
    __shared__ float ly[LPAIR * TPB * 2];
    __shared__ float lz[LPAIR * TPB * 2];   // 147456 B total
    __shared__ u64   wred[2][NWAVE];        // banked by k&1 (single-barrier loop)

    // ---- one-time staging: j<40 -> regs, j in [40,64) -> LDS (own-thread only) ----
    v2f rx[RPAIR], ry[RPAIR], rz[RPAIR];
#pragma unroll
    for (int p = 0; p < RPAIR; ++p) {
        const float* a = Pc + (size_t)(t + (2 * p) * TPB) * 3;
        const float* c = a + (size_t)TPB * 3;
        rx[p] = (v2f){a[0], c[0]};
        ry[p] = (v2f){a[1], c[1]};
        rz[p] = (v2f){a[2], c[2]};
    }
#pragma unroll
    for (int l = 0; l < LPAIR; ++l) {
        const float* a = Pc + (size_t)(t + (RPTS + 2 * l) * TPB) * 3;
        const float* c = a + (size_t)TPB * 3;
        const int idx = (l * TPB + t) * 2;
        lx[idx] = a[0]; lx[idx + 1] = c[0];   // same-thread RAW only: no barrier
        ly[idx] = a[1]; ly[idx + 1] = c[1];
        lz[idx] = a[2]; lz[idx + 1] = c[2];
    }

    const int start = start_p[0];
    float sx = P[(size_t)start * 3 + 0];
    float sy = P[(size_t)start * 3 + 1];
    float sz = P[(size_t)start * 3 + 2];
    if (r == 0 && t == 0) out[(size_t)b * NPTS] = start;

    v2f dist[NPAIR];
#pragma unroll
    for (int p = 0; p < NPAIR; ++p)
        dist[p] = (v2f){__builtin_inff(), __builtin_inff()};

    const int gbase = r * CHUNK;
    const unsigned bt = (unsigned)(gbase + t);

    for (int k = 1; k < NPTS; ++k) {
        const int bank = k & 1;
        const v2f s0 = (v2f){sx, sx}, s1 = (v2f){sy, sy}, s2 = (v2f){sz, sz};

        v2f vb[4];
#pragma unroll
        for (int q = 0; q < 4; ++q) vb[q] = (v2f){-1.0f, -1.0f};

        // ---- loop 1: pure packed math, no scalar argmax tracking ----
        // exact per-op rounding: (dx*dx + dy*dy) + dz*dz, contract off
#define PAIR_STEP(DP, PX, PY, PZ)                                        \
        {                                                                \
            v2f dx = (PX) - s0, dy = (PY) - s1, dz = (PZ) - s2;          \
            v2f d  = (dx * dx + dy * dy) + dz * dz;                      \
            v2f nd = vmin2(dist[DP], d);                                 \
            dist[DP] = nd;                                               \
            vb[(DP) >> 3] = vmax2(vb[(DP) >> 3], nd);                    \
        }

#pragma unroll
        for (int p = 0; p < RPAIR; ++p)
            PAIR_STEP(p, rx[p], ry[p], rz[p]);
#pragma unroll
        for (int l = 0; l < LPAIR; ++l) {
            const int idx = (l * TPB + t) * 2;
            v2f px = *reinterpret_cast<const v2f*>(&lx[idx]);   // ds_read_b64
            v2f py = *reinterpret_cast<const v2f*>(&ly[idx]);
            v2f pz = *reinterpret_cast<const v2f*>(&lz[idx]);
            PAIR_STEP(RPAIR + l, px, py, pz);
        }
#undef PAIR_STEP

        // block maxes -> wave-uniform best (float reduce, cheap)
        float m[4];
#pragma unroll
        for (int q = 0; q < 4; ++q) m[q] = fmaxf(vb[q].x, vb[q].y);
        float wbest = fmaxf(fmaxf(m[0], m[1]), fmaxf(m[2], m[3]));
#pragma unroll
        for (int o = 32; o >= 1; o >>= 1)
            wbest = fmaxf(wbest, __shfl_xor(wbest, o, 64));

        // block-skipped equality scan: recover lane-local first index
        // (ascending + min == first occurrence; exact bit equality)
        unsigned biL = 0xFFFFFFFFu;
#pragma unroll
        for (int q = 0; q < 4; ++q) {
            if (__any(m[q] == wbest)) {
#pragma unroll
                for (int p = 8 * q; p < 8 * q + 8; ++p) {
                    if (dist[p].x == wbest)
                        biL = min(biL, bt + (unsigned)((2 * p) * TPB));
                    if (dist[p].y == wbest)
                        biL = min(biL, bt + (unsigned)((2 * p + 1) * TPB));
                }
            }
        }

        // u32 min-reduce of index across the wave (wbest already uniform)
        unsigned bw = biL;
#pragma unroll
        for (int o = 32; o >= 1; o >>= 1) {
            unsigned q = (unsigned)__shfl_xor((int)bw, o, 64);
            bw = min(bw, q);
        }

        // wave key
        u64 wkey;
        if (PAYLOAD)
            wkey = ((u64)__float_as_uint(wbest) << 32) |
                   ((u64)(NN - 1 - bw) << 10) | (unsigned)k;
        else
            wkey = ((u64)__float_as_uint(wbest) << 32) | (unsigned)~bw;

        if (lane == 0) wred[bank][wv] = wkey;
        __syncthreads();

        // block reduce across 8 wave partials (every wave, no 2nd barrier)
        u64 v = wred[bank][lane & (NWAVE - 1)];
#pragma unroll
        for (int o = 1; o < NWAVE; o <<= 1) {
            u64 q = __shfl_xor(v, o, 64);
            if (q > v) v = q;
        }

        if (PAYLOAD) {
            const unsigned cwidx = NN - 1 - (unsigned)((v >> 10) & 0x1FFFFull);
            // unique owner lane of the wg-winning point publishes
            if (biL == cwidx) {
                u64* sb = bslots + ((size_t)k * WPB + r) * 4;
                __hip_atomic_store(sb + 3, v, __ATOMIC_RELAXED, __HIP_MEMORY_SCOPE_AGENT);
                const unsigned jj = (cwidx - bt) >> 9;   // TPB = 512
                float wx, wy, wz;
                if (jj >= RPTS) {
                    const int jl  = (int)jj - RPTS;
                    const int idx = ((jl >> 1) * TPB + t) * 2 + (jl & 1);
                    wx = lx[idx]; wy = ly[idx]; wz = lz[idx];
                } else {
                    const float* a = Pc + (size_t)(t + jj * TPB) * 3;  // L3-hot
                    wx = a[0]; wy = a[1]; wz = a[2];
                }
                const u64 kk = (u64)(unsigned)k;
                __hip_atomic_store(sb + 0, ((u64)__float_as_uint(wx) << 32) | kk,
                                   __ATOMIC_RELAXED, __HIP_MEMORY_SCOPE_AGENT);
                __hip_atomic_store(sb + 1, ((u64)__float_as_uint(wy) << 32) | kk,
                                   __ATOMIC_RELAXED, __HIP_MEMORY_SCOPE_AGENT);
                __hip_atomic_store(sb + 2, ((u64)__float_as_uint(wz) << 32) | kk,
                                   __ATOMIC_RELAXED, __HIP_MEMORY_SCOPE_AGENT);
            }

            // all lanes spin on rank (lane&3)'s key — cold line, relaxed
            const u64* sp = bslots + ((size_t)k * WPB + (lane & 3)) * 4;
            u64 g3;
            for (;;) {
                g3 = __hip_atomic_load(sp + 3, __ATOMIC_RELAXED, __HIP_MEMORY_SCOPE_AGENT);
                if ((unsigned)(g3 & 1023ull) == (unsigned)k) break;
                __builtin_amdgcn_s_sleep(1);
            }
#pragma unroll
            for (int o = 1; o <= 2; o <<= 1) {
                u64 q = __shfl_xor(g3, o, 64);
                if (q > g3) g3 = q;
            }
            const int widx = NN - 1 - (int)((g3 >> 10) & 0x1FFFFull);
            if (r == 0 && t == 0) out[(size_t)b * NPTS + k] = widx;

            // coords from the winning rank's slot (published concurrently)
            const u64* wp = bslots + ((size_t)k * WPB + (widx >> 15)) * 4;
            u64 c0, c1, c2;
            for (;;) {
                c0 = __hip_atomic_load(wp + 0, __ATOMIC_RELAXED, __HIP_MEMORY_SCOPE_AGENT);
                if ((unsigned)c0 == (unsigned)k) break;
                __builtin_amdgcn_s_sleep(1);
            }
            for (;;) {
                c1 = __hip_atomic_load(wp + 1, __ATOMIC_RELAXED, __HIP_MEMORY_SCOPE_AGENT);
                if ((unsigned)c1 == (unsigned)k) break;
            }
            for (;;) {
                c2 = __hip_atomic_load(wp + 2, __ATOMIC_RELAXED, __HIP_MEMORY_SCOPE_AGENT);
                if ((unsigned)c2 == (unsigned)k) break;
            }
            sx = __uint_as_float((unsigned)(c0 >> 32));
            sy = __uint_as_float((unsigned)(c1 >> 32));
            sz = __uint_as_float((unsigned)(c2 >> 32));
        } else {
            // R10-exact fallback: 1-word slot + uniform P[widx] reload
            if (t == 0)
                __hip_atomic_store(&bslots[(size_t)k * WPB + r], v,
                                   __ATOMIC_RELAXED, __HIP_MEMORY_SCOPE_AGENT);
            const u64* sp = &bslots[(size_t)k * WPB + (lane & 3)];
            u64 g;
            for (;;) {
                g = __hip_atomic_load(sp, __ATOMIC_RELAXED, __HIP_MEMORY_SCOPE_AGENT);
                if (g) break;
                __builtin_amdgcn_s_sleep(1);
            }
#pragma unroll
            for (int o = 1; o <= 2; o <<= 1) {
                u64 q = __shfl_xor(g, o, 64);
                if (q > g) g = q;
            }
            const int widx = (int)~(unsigned)g;
            if (r == 0 && t == 0) out[(size_t)b * NPTS + k] = widx;
            sx = P[(size_t)widx * 3 + 0];
            sy = P[(size_t)widx * 3 + 1];
            sz = P[(size_t)widx * 3 + 2];
        }
    }
}

extern "C" void kernel_launch(void* const* d_in, const int* in_sizes, int n_in,
                              void* d_out, int out_size, void* d_ws, size_t ws_size,
                              hipStream_t stream)
{
    const float* pos     = (const float*)d_in[0];
    const int*   start_p = (const int*)d_in[1];
    int*         out     = (int*)d_out;
    u64*         slots   = (u64*)d_ws;

    const size_t needP = (size_t)NB * NPTS * WPB * 4 * sizeof(u64);  // 8 MB
    const size_t need1 = (size_t)NB * NPTS * WPB * sizeof(u64);      // 2 MB

    void* args[] = { (void*)&pos, (void*)&start_p, (void*)&out, (void*)&slots };

    if (ws_size >= needP) {
        hipMemsetAsync(d_ws, 0, needP, stream);
        hipError_t e = hipLaunchCooperativeKernel(
            (const void*)fps_kernel<true>, dim3(NB * WPB), dim3(TPB),
            args, 0, stream);
        if (e != hipSuccess)
            fps_kernel<true><<<dim3(NB * WPB), dim3(TPB), 0, stream>>>(
                pos, start_p, out, slots);
    } else {
        hipMemsetAsync(d_ws, 0, need1, stream);
        hipError_t e = hipLaunchCooperativeKernel(
            (const void*)fps_kernel<false>, dim3(NB * WPB), dim3(TPB),
            args, 0, stream);
        if (e != hipSuccess)
            fps_kernel<false><<<dim3(NB * WPB), dim3(TPB), 0, stream>>>(
                pos, start_p, out, slots);
    }
}

// Round 12
// 3673.715 us; speedup vs baseline: 1.2391x; 1.2391x over previous
//
#include <hip/hip_runtime.h>
#include <stdint.h>

#define NB    64
#define NN    131072
#define NPTS  1024
#define TPB   512                  // 8 waves, 1 block/CU (R10-proven geometry)
#define WPB   4                    // workgroups per batch
#define NWAVE (TPB / 64)
#define CHUNK (NN / WPB)           // 32768 points per wg
#define PPT   (CHUNK / TPB)        // 64 points per thread
#define RPTS  40                   // register-resident points/thread
#define LPTS  24                   // LDS-resident points/thread (147456 B)
#define RPAIR (RPTS / 2)           // 20
#define LPAIR (LPTS / 2)           // 12
#define NPAIR (PPT / 2)            // 32 pairs, 4 scan-blocks of 8

typedef float v2f __attribute__((ext_vector_type(2)));
typedef unsigned long long u64;

static __device__ __forceinline__ v2f vmin2(v2f a, v2f b) {
#if __has_builtin(__builtin_elementwise_min)
    return __builtin_elementwise_min(a, b);
#else
    v2f r; r.x = fminf(a.x, b.x); r.y = fminf(a.y, b.y); return r;
#endif
}
static __device__ __forceinline__ v2f vmax2(v2f a, v2f b) {
#if __has_builtin(__builtin_elementwise_max)
    return __builtin_elementwise_max(a, b);
#else
    v2f r; r.x = fmaxf(a.x, b.x); r.y = fmaxf(a.y, b.y); return r;
#endif
}

// ---------------- inter-wg protocol (R10-proven): relaxed + cold slots -------
// One u64 slot per (batch, round k, rank): [dist_bits:32 | ~idx:32].
//   u64 max == (max dist, then min idx) == jnp.argmax first-occurrence.
//   ~idx != 0, so nonzero doubles as the publish flag (slots memset to 0).
// HW LESSONS: RELAXED atomics only (R4: acq/rel at agent scope = cache-
// maintenance storm, 118x). Never reuse a spin address within a launch (R5:
// stale polling). No payload words / two-stage spins (R8, R11 both regressed:
// each extra cold-line hop costs more than the uniform P[widx] reload).
// COMPUTE (R11-proven): argmax tracking hoisted out of the hot loop — loop1 is
// pure packed math (10 v_pk insts/pair) into 4 block-max accumulators; index
// recovered by a block-skipped equality scan (typically 1 of 4 blocks), then
// split float-max / u32-min wave reduces.

__global__ __launch_bounds__(TPB)
__attribute__((amdgpu_waves_per_eu(2, 2)))
void fps_kernel(
    const float* __restrict__ pos,
    const int*   __restrict__ start_p,
    int*         __restrict__ out,
    u64*         __restrict__ slots)
{
#pragma clang fp contract(off)
    const int wg   = blockIdx.x;
    const int xcd  = wg & 7;            // heuristic: keep a batch's 4 wgs on one XCD
    const int sl   = wg >> 3;
    const int b    = xcd * 8 + (sl >> 2);
    const int r    = sl & 3;
    const int t    = threadIdx.x;
    const int lane = t & 63;
    const int wv   = t >> 6;

    const float* __restrict__ P  = pos + (size_t)b * NN * 3;
    const float* __restrict__ Pc = P + (size_t)r * CHUNK * 3;
    u64* __restrict__ bslots = slots + (size_t)b * NPTS * WPB;

    // pair-packed LDS: coords of points (2l, 2l+1) adjacent -> ds_read_b64
    __shared__ float lx[LPAIR * TPB * 2];   // 49152 B
    __shared__ float ly[LPAIR * TPB * 2];
    __shared__ float lz[LPAIR * TPB * 2];   // 147456 B total
    __shared__ u64   wred[2][NWAVE];        // banked by k&1 (single-barrier loop)

    // ---- one-time staging: j<40 -> regs, j in [40,64) -> LDS (own-thread only) ----
    v2f rx[RPAIR], ry[RPAIR], rz[RPAIR];
#pragma unroll
    for (int p = 0; p < RPAIR; ++p) {
        const float* a = Pc + (size_t)(t + (2 * p) * TPB) * 3;
        const float* c = a + (size_t)TPB * 3;
        rx[p] = (v2f){a[0], c[0]};
        ry[p] = (v2f){a[1], c[1]};
        rz[p] = (v2f){a[2], c[2]};
    }
#pragma unroll
    for (int l = 0; l < LPAIR; ++l) {
        const float* a = Pc + (size_t)(t + (RPTS + 2 * l) * TPB) * 3;
        const float* c = a + (size_t)TPB * 3;
        const int idx = (l * TPB + t) * 2;
        lx[idx] = a[0]; lx[idx + 1] = c[0];   // same-thread RAW only: no barrier
        ly[idx] = a[1]; ly[idx + 1] = c[1];
        lz[idx] = a[2]; lz[idx + 1] = c[2];
    }

    const int start = start_p[0];
    float sx = P[(size_t)start * 3 + 0];
    float sy = P[(size_t)start * 3 + 1];
    float sz = P[(size_t)start * 3 + 2];
    if (r == 0 && t == 0) out[(size_t)b * NPTS] = start;

    v2f dist[NPAIR];
#pragma unroll
    for (int p = 0; p < NPAIR; ++p)
        dist[p] = (v2f){__builtin_inff(), __builtin_inff()};

    const int gbase = r * CHUNK;
    const unsigned bt = (unsigned)(gbase + t);

    for (int k = 1; k < NPTS; ++k) {
        const int bank = k & 1;
        const v2f s0 = (v2f){sx, sx}, s1 = (v2f){sy, sy}, s2 = (v2f){sz, sz};

        v2f vb[4];
#pragma unroll
        for (int q = 0; q < 4; ++q) vb[q] = (v2f){-1.0f, -1.0f};

        // ---- loop 1: pure packed math, no scalar argmax tracking ----
        // exact per-op rounding: (dx*dx + dy*dy) + dz*dz, contract off
#define PAIR_STEP(DP, PX, PY, PZ)                                        \
        {                                                                \
            v2f dx = (PX) - s0, dy = (PY) - s1, dz = (PZ) - s2;          \
            v2f d  = (dx * dx + dy * dy) + dz * dz;                      \
            v2f nd = vmin2(dist[DP], d);                                 \
            dist[DP] = nd;                                               \
            vb[(DP) >> 3] = vmax2(vb[(DP) >> 3], nd);                    \
        }

#pragma unroll
        for (int p = 0; p < RPAIR; ++p)
            PAIR_STEP(p, rx[p], ry[p], rz[p]);
#pragma unroll
        for (int l = 0; l < LPAIR; ++l) {
            const int idx = (l * TPB + t) * 2;
            v2f px = *reinterpret_cast<const v2f*>(&lx[idx]);   // ds_read_b64
            v2f py = *reinterpret_cast<const v2f*>(&ly[idx]);
            v2f pz = *reinterpret_cast<const v2f*>(&lz[idx]);
            PAIR_STEP(RPAIR + l, px, py, pz);
        }
#undef PAIR_STEP

        // block maxes -> wave-uniform best (float reduce, cheap)
        float m[4];
#pragma unroll
        for (int q = 0; q < 4; ++q) m[q] = fmaxf(vb[q].x, vb[q].y);
        float wbest = fmaxf(fmaxf(m[0], m[1]), fmaxf(m[2], m[3]));
#pragma unroll
        for (int o = 32; o >= 1; o >>= 1)
            wbest = fmaxf(wbest, __shfl_xor(wbest, o, 64));

        // block-skipped equality scan: recover lane-local first index
        // (ascending + min == first occurrence; exact bit equality)
        unsigned biL = 0xFFFFFFFFu;
#pragma unroll
        for (int q = 0; q < 4; ++q) {
            if (__any(m[q] == wbest)) {
#pragma unroll
                for (int p = 8 * q; p < 8 * q + 8; ++p) {
                    if (dist[p].x == wbest)
                        biL = min(biL, bt + (unsigned)((2 * p) * TPB));
                    if (dist[p].y == wbest)
                        biL = min(biL, bt + (unsigned)((2 * p + 1) * TPB));
                }
            }
        }

        // u32 min-reduce of index across the wave (wbest already uniform)
        unsigned bw = biL;
#pragma unroll
        for (int o = 32; o >= 1; o >>= 1) {
            unsigned q = (unsigned)__shfl_xor((int)bw, o, 64);
            bw = min(bw, q);
        }

        const u64 wkey = ((u64)__float_as_uint(wbest) << 32) | (unsigned)~bw;

        if (lane == 0) wred[bank][wv] = wkey;
        __syncthreads();

        // every wave reduces the 8 wave-partials itself (no 2nd barrier)
        u64 v = wred[bank][lane & (NWAVE - 1)];
#pragma unroll
        for (int o = 1; o < NWAVE; o <<= 1) {
            u64 q = __shfl_xor(v, o, 64);
            if (q > v) v = q;
        }
        if (t == 0)
            __hip_atomic_store(&bslots[(size_t)k * WPB + r], v,
                               __ATOMIC_RELAXED, __HIP_MEMORY_SCOPE_AGENT);

        // all lanes spin on rank (lane&3)'s slot — cold line, relaxed only
        const u64* sp = &bslots[(size_t)k * WPB + (lane & 3)];
        u64 g;
        for (;;) {
            g = __hip_atomic_load(sp, __ATOMIC_RELAXED, __HIP_MEMORY_SCOPE_AGENT);
            if (g) break;
            __builtin_amdgcn_s_sleep(1);
        }
#pragma unroll
        for (int o = 1; o <= 2; o <<= 1) {
            u64 q = __shfl_xor(g, o, 64);
            if (q > g) g = q;
        }
        const int widx = (int)~(unsigned)g;
        if (r == 0 && t == 0) out[(size_t)b * NPTS + k] = widx;
        // uniform address across lanes: one transaction per wave, L3-hot
        sx = P[(size_t)widx * 3 + 0];
        sy = P[(size_t)widx * 3 + 1];
        sz = P[(size_t)widx * 3 + 2];
    }
}

extern "C" void kernel_launch(void* const* d_in, const int* in_sizes, int n_in,
                              void* d_out, int out_size, void* d_ws, size_t ws_size,
                              hipStream_t stream)
{
    const float* pos     = (const float*)d_in[0];
    const int*   start_p = (const int*)d_in[1];
    int*         out     = (int*)d_out;
    u64*         slots   = (u64*)d_ws;

    // 64 batches x 1024 rounds x 4 ranks x 8 B = 2 MB; zeroed so nonzero == published
    hipMemsetAsync(d_ws, 0, (size_t)NB * NPTS * WPB * sizeof(u64), stream);

    void* args[] = { (void*)&pos, (void*)&start_p, (void*)&out, (void*)&slots };
    hipError_t e = hipLaunchCooperativeKernel((const void*)fps_kernel,
                                              dim3(NB * WPB), dim3(TPB),
                                              args, 0, stream);
    if (e != hipSuccess) {
        // 256 blocks of 512 thr = 1 block/CU: de-facto co-resident; same protocol.
        fps_kernel<<<dim3(NB * WPB), dim3(TPB), 0, stream>>>(pos, start_p, out, slots);
    }
}